// Round 2
// 659.246 us; speedup vs baseline: 1.0455x; 1.0455x over previous
//
#include <hip/hip_runtime.h>
#include <math.h>

#define BB 32          // pairs
#define SS 2048        // seq len
#define HH 1024        // hidden
#define NROWS (2 * BB * SS)   // 131072 row-dot-products
#define RPW 16                // rows per wave (contiguous)
#define NWAVES (NROWS / RPW)  // 8192 waves
#define NBLK (NWAVES / 4)     // 2048 blocks of 4 waves

// clang vector type — __builtin_nontemporal_load needs a real vector type,
// not HIP_vector_type<float,4>.
typedef float f4 __attribute__((ext_vector_type(4)));

// ---------------------------------------------------------------------------
// Kernel 1: rewards[row] = dot(hidden[row, :], w)
// Each wave owns 16 CONTIGUOUS rows (64 KB stream). Per-lane partials are
// accumulated register-only (no per-row cross-lane ops); one LDS-transpose
// reduction at the end replaces 16x6 serial shuffles. Non-temporal loads
// avoid allocating/evicting against the harness's dirty 2 GiB fill lines.
// ---------------------------------------------------------------------------
__device__ __forceinline__ float dot4(f4 a, f4 b) {
    return a.x * b.x + a.y * b.y + a.z * b.z + a.w * b.w;
}

__global__ __launch_bounds__(256) void rewards_kernel(
    const float* __restrict__ hs, const float* __restrict__ w,
    float* __restrict__ rewards)
{
    const int lane = threadIdx.x & 63;
    const int wid  = threadIdx.x >> 6;
    const int wave_id = blockIdx.x * 4 + wid;
    const size_t base = (size_t)wave_id * RPW;

    // lane covers h = lane*4 + k*256, k = 0..3 (covers 0..1023 exactly)
    f4 wv[4];
#pragma unroll
    for (int k = 0; k < 4; ++k)
        wv[k] = *reinterpret_cast<const f4*>(w + lane * 4 + k * 256);

    const float* rowp = hs + base * HH + lane * 4;

    float part[RPW];
#pragma unroll
    for (int r = 0; r < RPW; r += 2) {
        const f4* p0 = reinterpret_cast<const f4*>(rowp + (size_t)r * HH);
        const f4* p1 = reinterpret_cast<const f4*>(rowp + (size_t)(r + 1) * HH);
        // 8 independent 16B loads in flight per step; nt = no cache allocate
        f4 a0 = __builtin_nontemporal_load(p0);
        f4 a1 = __builtin_nontemporal_load(p0 + 64);
        f4 a2 = __builtin_nontemporal_load(p0 + 128);
        f4 a3 = __builtin_nontemporal_load(p0 + 192);
        f4 b0 = __builtin_nontemporal_load(p1);
        f4 b1 = __builtin_nontemporal_load(p1 + 64);
        f4 b2 = __builtin_nontemporal_load(p1 + 128);
        f4 b3 = __builtin_nontemporal_load(p1 + 192);
        part[r]     = dot4(a0, wv[0]) + dot4(a1, wv[1]) + dot4(a2, wv[2]) + dot4(a3, wv[3]);
        part[r + 1] = dot4(b0, wv[0]) + dot4(b1, wv[1]) + dot4(b2, wv[2]) + dot4(b3, wv[3]);
    }

    // One LDS-transpose reduction for all 16 rows.
    // Layout: red[wid][lane*17 + r]  (stride 17 -> conflict-free writes,
    // 2-way (free) reads).
    __shared__ float red[4][64 * 17];
    float* rw = red[wid];
#pragma unroll
    for (int r = 0; r < RPW; ++r)
        rw[lane * 17 + r] = part[r];
    __syncthreads();   // also drains lgkmcnt; waves are independent otherwise

    const int row = lane & 15;   // which of the 16 rows this lane reduces
    const int c   = lane >> 4;   // which 16-lane chunk it sums
    float s = 0.f;
#pragma unroll
    for (int j = 0; j < 16; ++j)
        s += rw[(c * 16 + j) * 17 + row];
    // combine the 4 chunk-partials (lanes row, row+16, row+32, row+48)
    s += __shfl_xor(s, 16, 64);
    s += __shfl_xor(s, 32, 64);
    if (lane < 16)
        rewards[base + lane] = s;   // 16 consecutive floats, coalesced
}

// ---------------------------------------------------------------------------
// Block-wide helpers (256 threads)
// ---------------------------------------------------------------------------
__device__ __forceinline__ int block_min_i(int v, int* sm, int tid) {
    sm[tid] = v;
    __syncthreads();
    for (int s = 128; s > 0; s >>= 1) {
        if (tid < s) sm[tid] = min(sm[tid], sm[tid + s]);
        __syncthreads();
    }
    int r = sm[0];
    __syncthreads();
    return r;
}

__device__ __forceinline__ float block_sum_f(float v, float* sm, int tid) {
    sm[tid] = v;
    __syncthreads();
    for (int s = 128; s > 0; s >>= 1) {
        if (tid < s) sm[tid] += sm[tid + s];
        __syncthreads();
    }
    float r = sm[0];
    __syncthreads();
    return r;
}

// ---------------------------------------------------------------------------
// Kernel 2: one block per pair b.
// ---------------------------------------------------------------------------
__global__ __launch_bounds__(256) void pair_kernel(
    const int* __restrict__ ids, const float* __restrict__ rewards,
    float* __restrict__ out, float* __restrict__ pp, float* __restrict__ accf)
{
    const int b = blockIdx.x;
    const int tid = threadIdx.x;
    const int* ic = ids + b * SS;
    const int* ir = ids + (BB + b) * SS;
    const float* rc = rewards + b * SS;
    const float* rr = rewards + (BB + b) * SS;

    __shared__ int smi[256];
    __shared__ float smf[256];

    int cmin = SS, rmin = SS, dmin = SS;
    for (int i = tid; i < SS; i += 256) {
        int a = ic[i];
        int c = ir[i];
        if (a == 0 && i < cmin) cmin = i;
        if (c == 0 && i < rmin) rmin = i;
        if (a != c && i < dmin) dmin = i;
    }
    const int c_ind     = block_min_i(cmin, smi, tid);
    const int r_ind_pad = block_min_i(rmin, smi, tid);
    const int dv        = block_min_i(dmin, smi, tid);

    const bool has_div = (dv < SS);
    const int div_ind = has_div ? dv : (SS - 1);
    const int r_ind   = has_div ? r_ind_pad : c_ind;
    const int end_ind = has_div ? max(c_ind, r_ind_pad) : SS;
    const float cnt = fmaxf((float)(end_ind - div_ind), 1.0f);

    float s1 = 0.f, s2 = 0.f, s3 = 0.f;
    for (int i = div_ind + tid; i < end_ind; i += 256) {
        const float c = rc[i];
        const float r = rr[i];
        const float x = c - r;
        // numerically-stable log_sigmoid
        s1 += fminf(x, 0.f) - log1pf(expf(-fabsf(x)));
        s2 += 1.f / (1.f + expf(-c));
        s3 += 1.f / (1.f + expf(-r));
    }
    s1 = block_sum_f(s1, smf, tid);
    s2 = block_sum_f(s2, smf, tid);
    s3 = block_sum_f(s3, smf, tid);

    if (tid == 0) {
        pp[b] = s1 / cnt;
        const float diff_score = (s2 - s3) / cnt;
        accf[b] = (diff_score > 0.5f) ? 1.f : 0.f;
        out[2 + b]      = rc[c_ind - 1];   // chosen_mean_score
        out[2 + BB + b] = rr[r_ind - 1];   // rejected_mean_score
    }
}

// ---------------------------------------------------------------------------
// Kernel 3: final reduction over 32 pairs -> loss, acc
// ---------------------------------------------------------------------------
__global__ __launch_bounds__(64) void final_kernel(
    const float* __restrict__ pp, const float* __restrict__ accf,
    float* __restrict__ out)
{
    const int lane = threadIdx.x;
    float v = (lane < BB) ? pp[lane] : 0.f;
    float a = (lane < BB) ? accf[lane] : 0.f;
#pragma unroll
    for (int off = 32; off > 0; off >>= 1) {
        v += __shfl_xor(v, off, 64);
        a += __shfl_xor(a, off, 64);
    }
    if (lane == 0) {
        out[0] = -v;   // loss
        out[1] = a;    // acc (read back as float32)
    }
}

extern "C" void kernel_launch(void* const* d_in, const int* in_sizes, int n_in,
                              void* d_out, int out_size, void* d_ws, size_t ws_size,
                              hipStream_t stream) {
    const int*   ids = (const int*)d_in[0];     // (2B, S) int32
    const float* hs  = (const float*)d_in[1];   // (2B, S, H) fp32
    const float* w   = (const float*)d_in[2];   // (H,) fp32
    float* out = (float*)d_out;                 // 66 floats: loss, acc, chosen[32], rejected[32]

    float* rewards = (float*)d_ws;              // 2B*S floats = 512 KiB
    float* pp      = rewards + NROWS;           // 32 floats
    float* accf    = pp + BB;                   // 32 floats

    rewards_kernel<<<NBLK, 256, 0, stream>>>(hs, w, rewards);
    pair_kernel<<<BB, 256, 0, stream>>>(ids, rewards, out, pp, accf);
    final_kernel<<<1, 64, 0, stream>>>(pp, accf, out);
}